// Round 8
// baseline (5423.944 us; speedup 1.0000x reference)
//
#include <hip/hip_runtime.h>
#include <hip/hip_bf16.h>

namespace {

constexpr int B = 1024, T = 512, H = 60, G = 180;
constexpr int NTHR = 192;
constexpr int NB = 4;          // batch elements per vec block
constexpr int TT = 8;          // x-tile depth
constexpr int NT = T / TT;
constexpr int WSTR = 68;       // LDS weight row stride (== 4 mod 32 -> balanced banks)

__device__ __forceinline__ float sigm(float x) { return 1.f / (1.f + __expf(-x)); }
__device__ __forceinline__ float tanh_fast(float x) {
  x = fminf(fmaxf(x, -15.f), 15.f);
  const float e = __expf(-2.f * x);
  return (1.f - e) / (1.f + e);
}

__device__ __forceinline__ float ldcvt(const float* p) { return *p; }
__device__ __forceinline__ float ldcvt(const __hip_bfloat16* p) { return __bfloat162float(*p); }
__device__ __forceinline__ void stcvt(float* p, float v) { *p = v; }
__device__ __forceinline__ void stcvt(__hip_bfloat16* p, float v) { *p = __float2bfloat16(v); }

// ---------------------------------------------------------------------------
// Scalar-input GRU layer (F=1). Proven: 62 us, weights register-resident.
// ---------------------------------------------------------------------------
#define ACCH(i, dst)                                                  \
  {                                                                   \
    const float4 hv = *(const float4*)&h_sh[(i) * 4];                 \
    dst = fmaf(Wh##i.x, hv.x, dst);                                   \
    dst = fmaf(Wh##i.y, hv.y, dst);                                   \
    dst = fmaf(Wh##i.z, hv.z, dst);                                   \
    dst = fmaf(Wh##i.w, hv.w, dst);                                   \
  }

template <typename TS, bool WRITE_YS, bool WRITE_ENC>
__global__ __launch_bounds__(NTHR, 1) void gru_scalar_kernel(
    const float* __restrict__ xscalar,  // [B][T]
    const float* __restrict__ Wih,      // [180][1]
    const float* __restrict__ Whh,      // [180][60]
    const float* __restrict__ bih, const float* __restrict__ bhh,
    const float* __restrict__ h_init,   // nullptr => zeros; [b*180 + j]
    TS* __restrict__ ys_out,            // [T][B][H]
    float* __restrict__ enc_out)        // pre-offset by slot; [b*180 + j]
{
  const int tid = threadIdx.x;
  const int b = blockIdx.x;

  __shared__ __align__(16) float h_sh[64];
  __shared__ float Ar[60], Az[60], Nn[60], Hn[60];
  __shared__ float xs_seq[T];

  const int rr = (tid < G) ? tid : 0;

  float4 Wh0, Wh1, Wh2, Wh3, Wh4, Wh5, Wh6, Wh7, Wh8, Wh9, Wh10, Wh11, Wh12, Wh13, Wh14;
#define LWH(i) Wh##i = *(const float4*)&Whh[(size_t)rr * H + (i) * 4];
  LWH(0) LWH(1) LWH(2) LWH(3) LWH(4) LWH(5) LWH(6) LWH(7)
  LWH(8) LWH(9) LWH(10) LWH(11) LWH(12) LWH(13) LWH(14)
#undef LWH
  const float wih0 = Wih[rr];
  const float bi = bih[rr];
  const float bh = bhh[rr];

  if (tid < H) h_sh[tid] = h_init ? h_init[(size_t)b * G + tid] : 0.f;
  if (tid >= H && tid < 64) h_sh[tid] = 0.f;
  for (int i = tid; i < T; i += NTHR) xs_seq[i] = xscalar[(size_t)b * T + i];
  __syncthreads();

  const int g = tid / H;
  const int j = tid - g * H;

  for (int t = 0; t < T; ++t) {
    if (tid < G) {
      float c0 = bh, c1 = 0.f, c2 = 0.f, c3 = 0.f;
      ACCH(0, c0) ACCH(1, c1) ACCH(2, c2) ACCH(3, c3)
      ACCH(4, c0) ACCH(5, c1) ACCH(6, c2) ACCH(7, c3)
      ACCH(8, c0) ACCH(9, c1) ACCH(10, c2) ACCH(11, c3)
      ACCH(12, c0) ACCH(13, c1) ACCH(14, c2)
      const float c = (c0 + c1) + (c2 + c3);
      const float a = fmaf(wih0, xs_seq[t], bi);
      if (g == 0)       Ar[j] = a + c;
      else if (g == 1)  Az[j] = a + c;
      else            { Nn[j] = a; Hn[j] = c; }
    }
    __syncthreads();

    if (tid < H) {
      const float rg = sigm(Ar[tid]);
      const float zg = sigm(Az[tid]);
      const float nv = tanh_fast(fmaf(rg, Hn[tid], Nn[tid]));
      const float hnew = fmaf(zg, h_sh[tid] - nv, nv);
      h_sh[tid] = hnew;
      if constexpr (WRITE_YS)
        stcvt(&ys_out[(size_t)t * B * H + (size_t)b * H + tid], hnew);
    }
    __syncthreads();
  }

  if constexpr (WRITE_ENC) {
    if (tid < H) enc_out[(size_t)b * G + tid] = h_sh[tid];
  }
}

// ---------------------------------------------------------------------------
// Vector-input GRU layer, LDS-weights + NB=4 batch:
//   grid 256 blocks (b0 = blockIdx*4), 192 threads. Wih & Whh staged to LDS
//   once (row stride 68: 68 mod 32 == 4 -> 64 different-row ds_read_b128
//   land 8 words/bank = throughput floor). Thread r<180 computes ih+hh dots
//   for ALL 4 batch elems (8 indep FMA chains, 480 FMA/thread/step) -- 4x
//   the FMAs per weight byte; x/h reads are wave-broadcast (free).
//   VGPR need ~60 (8 acc + transients): no register-residency battle, and
//   LDS loads can't be hoisted across __syncthreads -> nothing to spill.
//   x tiles (8 steps) double-buffered via 10 reg prefetches.
//   c3's linear head: threads 180-183 (idle in phase 1) dot lin_W (in LDS,
//   NOT registers: would add +60 VGPR pressure kernel-wide) with h[b].
// ---------------------------------------------------------------------------
template <typename TS, bool WRITE_YS, bool WRITE_ENC, bool WRITE_PRED>
__global__ __launch_bounds__(NTHR, 1) void gru_vec4_kernel(
    const TS* __restrict__ xseq,        // [T][B][H]
    const float* __restrict__ Wih,      // [180][60]
    const float* __restrict__ Whh,      // [180][60]
    const float* __restrict__ bih, const float* __restrict__ bhh,
    const float* __restrict__ h_init,   // nullptr => zeros; [b*180 + j]
    TS* __restrict__ ys_out,            // [T][B][H]
    float* __restrict__ enc_out,        // pre-offset by slot; [b*180 + j]
    float* __restrict__ pred_out,       // [B][T]
    const float* __restrict__ linW,     // [60]
    const float* __restrict__ linb)     // [1]
{
  const int tid = threadIdx.x;
  const int b0 = blockIdx.x * NB;

  __shared__ __align__(16) float wih_l[G][WSTR];    // 48.96 KB
  __shared__ __align__(16) float whh_l[G][WSTR];    // 48.96 KB
  __shared__ __align__(16) float x_l[2][TT * NB * H];  // 15.36 KB
  __shared__ __align__(16) float h_l[NB][WSTR];
  __shared__ float gates_l[NB][4][64];              // r,z,n_i,n_h
  __shared__ float lw_l[64];

  // ---- stage weights into LDS (coalesced; L2-served, once) ----
  for (int i = tid; i < G * H; i += NTHR) {
    const int r = i / H, k = i - r * H;
    wih_l[r][k] = Wih[i];
    whh_l[r][k] = Whh[i];
  }
  // ---- init h ----
  for (int i = tid; i < NB * WSTR; i += NTHR) {
    const int b = i / WSTR, j = i - b * WSTR;
    float hv = 0.f;
    if (j < H && h_init) hv = h_init[(size_t)(b0 + b) * G + j];
    h_l[b][j] = hv;
  }
  float lb = 0.f;
  if constexpr (WRITE_PRED) {
    if (tid < H) lw_l[tid] = linW[tid];
    lb = linb[0];
  }

  const int rr = (tid < G) ? tid : 0;
  const float bi = bih[rr];
  const float bh = bhh[rr];
  const int g = rr / H;
  const int j = rr - g * H;

  // ---- stage x tile 0 ----
#define XGADDR(f, t0) ((((size_t)((t0) + (f) / (NB * H)) * B + b0) * H) + ((f) % (NB * H)))
  {
#pragma unroll
    for (int q = 0; q < 10; ++q) {
      const int f = q * NTHR + tid;
      x_l[0][f] = ldcvt(&xseq[XGADDR(f, 0)]);
    }
  }
  __syncthreads();

  for (int tile = 0; tile < NT; ++tile) {
    const int cur = tile & 1, nxt = cur ^ 1;

    // ---- prefetch next tile into 10 named regs (hidden under 8 steps) ----
    float p0 = 0, p1 = 0, p2 = 0, p3 = 0, p4 = 0, p5 = 0, p6 = 0, p7 = 0, p8 = 0, p9 = 0;
    if (tile + 1 < NT) {
      const int t0 = (tile + 1) * TT;
#define PF(q) p##q = ldcvt(&xseq[XGADDR(q * NTHR + tid, t0)]);
      PF(0) PF(1) PF(2) PF(3) PF(4) PF(5) PF(6) PF(7) PF(8) PF(9)
#undef PF
    }

    for (int s = 0; s < TT; ++s) {
      const int t = tile * TT + s;

      // ================= phase 1: dots =================
      if (tid < G) {
        float a0 = bi, a1 = bi, a2 = bi, a3 = bi;
        float c0 = bh, c1 = bh * 0.f, c2 = 0.f, c3 = 0.f;
        // note: c1..c3 accumulate from 0; bh folded into c0 only -- but each
        // acc is per-b! Fold bh into each b's total at the end instead.
        a0 = bi; a1 = bi; a2 = bi; a3 = bi;
        c0 = 0.f; c1 = 0.f; c2 = 0.f; c3 = 0.f;
        const float* xb = &x_l[cur][s * (NB * H)];
#pragma unroll
        for (int k = 0; k < 15; ++k) {
          const float4 wi = *(const float4*)&wih_l[rr][4 * k];
          const float4 wh = *(const float4*)&whh_l[rr][4 * k];
          const float4 x0 = *(const float4*)&xb[0 * H + 4 * k];
          const float4 x1 = *(const float4*)&xb[1 * H + 4 * k];
          const float4 x2 = *(const float4*)&xb[2 * H + 4 * k];
          const float4 x3 = *(const float4*)&xb[3 * H + 4 * k];
          const float4 h0 = *(const float4*)&h_l[0][4 * k];
          const float4 h1 = *(const float4*)&h_l[1][4 * k];
          const float4 h2 = *(const float4*)&h_l[2][4 * k];
          const float4 h3 = *(const float4*)&h_l[3][4 * k];
          a0 = fmaf(wi.x, x0.x, a0); a0 = fmaf(wi.y, x0.y, a0);
          a0 = fmaf(wi.z, x0.z, a0); a0 = fmaf(wi.w, x0.w, a0);
          a1 = fmaf(wi.x, x1.x, a1); a1 = fmaf(wi.y, x1.y, a1);
          a1 = fmaf(wi.z, x1.z, a1); a1 = fmaf(wi.w, x1.w, a1);
          a2 = fmaf(wi.x, x2.x, a2); a2 = fmaf(wi.y, x2.y, a2);
          a2 = fmaf(wi.z, x2.z, a2); a2 = fmaf(wi.w, x2.w, a2);
          a3 = fmaf(wi.x, x3.x, a3); a3 = fmaf(wi.y, x3.y, a3);
          a3 = fmaf(wi.z, x3.z, a3); a3 = fmaf(wi.w, x3.w, a3);
          c0 = fmaf(wh.x, h0.x, c0); c0 = fmaf(wh.y, h0.y, c0);
          c0 = fmaf(wh.z, h0.z, c0); c0 = fmaf(wh.w, h0.w, c0);
          c1 = fmaf(wh.x, h1.x, c1); c1 = fmaf(wh.y, h1.y, c1);
          c1 = fmaf(wh.z, h1.z, c1); c1 = fmaf(wh.w, h1.w, c1);
          c2 = fmaf(wh.x, h2.x, c2); c2 = fmaf(wh.y, h2.y, c2);
          c2 = fmaf(wh.z, h2.z, c2); c2 = fmaf(wh.w, h2.w, c2);
          c3 = fmaf(wh.x, h3.x, c3); c3 = fmaf(wh.y, h3.y, c3);
          c3 = fmaf(wh.z, h3.z, c3); c3 = fmaf(wh.w, h3.w, c3);
        }
        c0 += bh; c1 += bh; c2 += bh; c3 += bh;
        if (g == 2) {
          gates_l[0][2][j] = a0; gates_l[0][3][j] = c0;
          gates_l[1][2][j] = a1; gates_l[1][3][j] = c1;
          gates_l[2][2][j] = a2; gates_l[2][3][j] = c2;
          gates_l[3][2][j] = a3; gates_l[3][3][j] = c3;
        } else {
          gates_l[0][g][j] = a0 + c0;
          gates_l[1][g][j] = a1 + c1;
          gates_l[2][g][j] = a2 + c2;
          gates_l[3][g][j] = a3 + c3;
        }
      } else if constexpr (WRITE_PRED) {
        // threads 180-183: linear head for step t-1 (h = post-step-(t-1))
        if (tid < 184 && t > 0) {
          const int bq = tid - 180;
          float s0 = 0, s1 = 0, s2 = 0, s3 = 0;
#pragma unroll
          for (int k = 0; k < 15; ++k) {
            const float4 lw = *(const float4*)&lw_l[4 * k];
            const float4 hv = *(const float4*)&h_l[bq][4 * k];
            s0 = fmaf(lw.x, hv.x, s0); s1 = fmaf(lw.y, hv.y, s1);
            s2 = fmaf(lw.z, hv.z, s2); s3 = fmaf(lw.w, hv.w, s3);
          }
          pred_out[(size_t)(b0 + bq) * T + (t - 1)] = (s0 + s1) + (s2 + s3) + lb;
        }
      }
      __syncthreads();

      // ================= phase 2: activations (+x-tile commit at s==7) ====
      {
        // 240 units over 192 threads
#pragma unroll
        for (int rep = 0; rep < 2; ++rep) {
          const int u = tid + rep * NTHR;
          if (u < NB * H) {
            const int b = u / H, jj = u - b * H;
            const float pr = gates_l[b][0][jj];
            const float pz = gates_l[b][1][jj];
            const float pa = gates_l[b][2][jj];
            const float pc = gates_l[b][3][jj];
            const float rg = sigm(pr), zg = sigm(pz);
            const float nv = tanh_fast(fmaf(rg, pc, pa));
            const float hold = h_l[b][jj];
            const float hnew = fmaf(zg, hold - nv, nv);
            h_l[b][jj] = hnew;
            if constexpr (WRITE_YS)
              stcvt(&ys_out[((size_t)t * B + b0 + b) * H + jj], hnew);
          }
        }
        if (s == TT - 1) {
          // commit prefetched x into the other buffer
          x_l[nxt][0 * NTHR + tid] = p0; x_l[nxt][1 * NTHR + tid] = p1;
          x_l[nxt][2 * NTHR + tid] = p2; x_l[nxt][3 * NTHR + tid] = p3;
          x_l[nxt][4 * NTHR + tid] = p4; x_l[nxt][5 * NTHR + tid] = p5;
          x_l[nxt][6 * NTHR + tid] = p6; x_l[nxt][7 * NTHR + tid] = p7;
          x_l[nxt][8 * NTHR + tid] = p8; x_l[nxt][9 * NTHR + tid] = p9;
        }
      }
      __syncthreads();
    }
  }

  // ---- epilogue: pred for t = T-1; enc writes ----
  if constexpr (WRITE_PRED) {
    if (tid >= G && tid < G + NB) {
      const int bq = tid - G;
      float s0 = 0, s1 = 0, s2 = 0, s3 = 0;
#pragma unroll
      for (int k = 0; k < 15; ++k) {
        const float4 lw = *(const float4*)&lw_l[4 * k];
        const float4 hv = *(const float4*)&h_l[bq][4 * k];
        s0 = fmaf(lw.x, hv.x, s0); s1 = fmaf(lw.y, hv.y, s1);
        s2 = fmaf(lw.z, hv.z, s2); s3 = fmaf(lw.w, hv.w, s3);
      }
      pred_out[(size_t)(b0 + bq) * T + (T - 1)] = (s0 + s1) + (s2 + s3) + lb;
    }
  }
  if constexpr (WRITE_ENC) {
#pragma unroll
    for (int rep = 0; rep < 2; ++rep) {
      const int u = tid + rep * NTHR;
      if (u < NB * H) {
        const int b = u / H, jj = u - b * H;
        enc_out[(size_t)(b0 + b) * G + jj] = h_l[b][jj];
      }
    }
  }
#undef XGADDR
}

template <typename TS>
void launch_all(const float* inputs, const float* outputs,
                const float* eW_ih0, const float* eW_hh0, const float* eb_ih0, const float* eb_hh0,
                const float* eW_ih1, const float* eW_hh1, const float* eb_ih1, const float* eb_hh1,
                const float* eW_ih2, const float* eW_hh2, const float* eb_ih2, const float* eb_hh2,
                const float* c1_Wih, const float* c1_Whh, const float* c1_bih, const float* c1_bhh,
                const float* c2_Wih, const float* c2_Whh, const float* c2_bih, const float* c2_bhh,
                const float* c3_Wih, const float* c3_Whh, const float* c3_bih, const float* c3_bhh,
                const float* lin_W, const float* lin_b,
                float* pred, float* enc, void* d_ws, hipStream_t stream) {
  const size_t seq = (size_t)T * B * H;
  TS* ws0 = (TS*)d_ws;
  TS* ws1 = ws0 + seq;
  const dim3 gs(B), gv(B / NB), blk(NTHR);

  // encoder
  gru_scalar_kernel<TS, true, true><<<gs, blk, 0, stream>>>(
      inputs, eW_ih0, eW_hh0, eb_ih0, eb_hh0, nullptr, ws0, enc + 0);
  gru_vec4_kernel<TS, true, true, false><<<gv, blk, 0, stream>>>(
      ws0, eW_ih1, eW_hh1, eb_ih1, eb_hh1, nullptr,
      ws1, enc + 60, nullptr, nullptr, nullptr);
  gru_vec4_kernel<TS, false, true, false><<<gv, blk, 0, stream>>>(
      ws1, eW_ih2, eW_hh2, eb_ih2, eb_hh2, nullptr,
      nullptr, enc + 120, nullptr, nullptr, nullptr);
  // decoder: h1<-enc[2], h2<-enc[1], h3<-enc[0]
  gru_scalar_kernel<TS, true, false><<<gs, blk, 0, stream>>>(
      outputs, c1_Wih, c1_Whh, c1_bih, c1_bhh, enc + 120, ws0, nullptr);
  gru_vec4_kernel<TS, true, false, false><<<gv, blk, 0, stream>>>(
      ws0, c2_Wih, c2_Whh, c2_bih, c2_bhh, enc + 60,
      ws1, nullptr, nullptr, nullptr, nullptr);
  gru_vec4_kernel<TS, false, false, true><<<gv, blk, 0, stream>>>(
      ws1, c3_Wih, c3_Whh, c3_bih, c3_bhh, enc + 0,
      nullptr, nullptr, pred, lin_W, lin_b);
}

}  // namespace

extern "C" void kernel_launch(void* const* d_in, const int* in_sizes, int n_in,
                              void* d_out, int out_size, void* d_ws, size_t ws_size,
                              hipStream_t stream) {
  const float* inputs  = (const float*)d_in[0];
  const float* outputs = (const float*)d_in[1];
  const float* eW_ih0 = (const float*)d_in[2];  const float* eW_hh0 = (const float*)d_in[3];
  const float* eb_ih0 = (const float*)d_in[4];  const float* eb_hh0 = (const float*)d_in[5];
  const float* eW_ih1 = (const float*)d_in[6];  const float* eW_hh1 = (const float*)d_in[7];
  const float* eb_ih1 = (const float*)d_in[8];  const float* eb_hh1 = (const float*)d_in[9];
  const float* eW_ih2 = (const float*)d_in[10]; const float* eW_hh2 = (const float*)d_in[11];
  const float* eb_ih2 = (const float*)d_in[12]; const float* eb_hh2 = (const float*)d_in[13];
  const float* c1_Wih = (const float*)d_in[14]; const float* c1_Whh = (const float*)d_in[15];
  const float* c1_bih = (const float*)d_in[16]; const float* c1_bhh = (const float*)d_in[17];
  const float* c2_Wih = (const float*)d_in[18]; const float* c2_Whh = (const float*)d_in[19];
  const float* c2_bih = (const float*)d_in[20]; const float* c2_bhh = (const float*)d_in[21];
  const float* c3_Wih = (const float*)d_in[22]; const float* c3_Whh = (const float*)d_in[23];
  const float* c3_bih = (const float*)d_in[24]; const float* c3_bhh = (const float*)d_in[25];
  const float* lin_W  = (const float*)d_in[26]; const float* lin_b  = (const float*)d_in[27];

  float* pred = (float*)d_out;                 // [B][T]
  float* enc  = pred + (size_t)B * T;          // [B][3][60]

  const size_t seq = (size_t)T * B * H;

#define ARGS inputs, outputs, \
    eW_ih0, eW_hh0, eb_ih0, eb_hh0, eW_ih1, eW_hh1, eb_ih1, eb_hh1, \
    eW_ih2, eW_hh2, eb_ih2, eb_hh2, \
    c1_Wih, c1_Whh, c1_bih, c1_bhh, c2_Wih, c2_Whh, c2_bih, c2_bhh, \
    c3_Wih, c3_Whh, c3_bih, c3_bhh, lin_W, lin_b, pred, enc, d_ws, stream

  if (ws_size >= 2 * seq * sizeof(float)) {
    launch_all<float>(ARGS);            // 252 MB (known to fit)
  } else {
    launch_all<__hip_bfloat16>(ARGS);   // 126 MB fallback
  }
#undef ARGS
}

// Round 9
// 3324.015 us; speedup vs baseline: 1.6317x; 1.6317x over previous
//
#include <hip/hip_runtime.h>
#include <hip/hip_bf16.h>

namespace {

constexpr int B = 1024, T = 512, H = 60, G = 180, NTHR = 192;

__device__ __forceinline__ float sigm(float x) { return 1.f / (1.f + __expf(-x)); }
__device__ __forceinline__ float tanh_fast(float x) {
  x = fminf(fmaxf(x, -15.f), 15.f);
  const float e = __expf(-2.f * x);
  return (1.f - e) / (1.f + e);
}

// ---------------------------------------------------------------------------
// Scalar-input GRU layer (F=1). PROVEN shape: 62 us, 88 VGPR, weights stay
// register-resident. Do not perturb.
// ---------------------------------------------------------------------------
#define ACCH(i, dst)                                                  \
  {                                                                   \
    const float4 hv = *(const float4*)&h_sh[(i) * 4];                 \
    dst = fmaf(Wh##i.x, hv.x, dst);                                   \
    dst = fmaf(Wh##i.y, hv.y, dst);                                   \
    dst = fmaf(Wh##i.z, hv.z, dst);                                   \
    dst = fmaf(Wh##i.w, hv.w, dst);                                   \
  }

template <bool WRITE_YS, bool WRITE_ENC>
__global__ __launch_bounds__(NTHR, 1) void gru_scalar_kernel(
    const float* __restrict__ xscalar,  // [B][T]
    const float* __restrict__ Wih,      // [180][1]
    const float* __restrict__ Whh,      // [180][60]
    const float* __restrict__ bih, const float* __restrict__ bhh,
    const float* __restrict__ h_init,   // nullptr => zeros; [b*180 + j]
    float* __restrict__ ys_out,         // [T][B][60]
    float* __restrict__ enc_out)        // pre-offset by slot; [b*180 + j]
{
  const int tid = threadIdx.x;
  const int b = blockIdx.x;

  __shared__ __align__(16) float h_sh[64];
  __shared__ float Ar[60], Az[60], Nn[60], Hn[60];
  __shared__ float xs_seq[T];

  const int rr = (tid < G) ? tid : 0;

  float4 Wh0, Wh1, Wh2, Wh3, Wh4, Wh5, Wh6, Wh7, Wh8, Wh9, Wh10, Wh11, Wh12, Wh13, Wh14;
#define LWH(i) Wh##i = *(const float4*)&Whh[(size_t)rr * H + (i) * 4];
  LWH(0) LWH(1) LWH(2) LWH(3) LWH(4) LWH(5) LWH(6) LWH(7)
  LWH(8) LWH(9) LWH(10) LWH(11) LWH(12) LWH(13) LWH(14)
#undef LWH
  const float wih0 = Wih[rr];
  const float bi = bih[rr];
  const float bh = bhh[rr];

  if (tid < H) h_sh[tid] = h_init ? h_init[(size_t)b * G + tid] : 0.f;
  if (tid >= H && tid < 64) h_sh[tid] = 0.f;
  for (int i = tid; i < T; i += NTHR) xs_seq[i] = xscalar[(size_t)b * T + i];
  __syncthreads();

  const int g = tid / H;
  const int j = tid - g * H;

  for (int t = 0; t < T; ++t) {
    if (tid < G) {
      float c0 = bh, c1 = 0.f, c2 = 0.f, c3 = 0.f;
      ACCH(0, c0) ACCH(1, c1) ACCH(2, c2) ACCH(3, c3)
      ACCH(4, c0) ACCH(5, c1) ACCH(6, c2) ACCH(7, c3)
      ACCH(8, c0) ACCH(9, c1) ACCH(10, c2) ACCH(11, c3)
      ACCH(12, c0) ACCH(13, c1) ACCH(14, c2)
      const float c = (c0 + c1) + (c2 + c3);
      const float a = fmaf(wih0, xs_seq[t], bi);
      if (g == 0)       Ar[j] = a + c;
      else if (g == 1)  Az[j] = a + c;
      else            { Nn[j] = a; Hn[j] = c; }
    }
    __syncthreads();

    if (tid < H) {
      const float rg = sigm(Ar[tid]);
      const float zg = sigm(Az[tid]);
      const float nv = tanh_fast(fmaf(rg, Hn[tid], Nn[tid]));
      const float hnew = fmaf(zg, h_sh[tid] - nv, nv);
      h_sh[tid] = hnew;
      if constexpr (WRITE_YS)
        ys_out[(size_t)t * B * H + (size_t)b * H + tid] = hnew;
    }
    __syncthreads();
  }

  if constexpr (WRITE_ENC) {
    if (tid < H) enc_out[(size_t)b * G + tid] = h_sh[tid];
  }
}

// ---------------------------------------------------------------------------
// gi GEMM (fully parallel, no recurrence): gi[row][r] = bih[r] + Wih[r].x[row]
// row = t*B+b flattened over a T-chunk. Block: 192 thr, 16 rows. Thread r
// holds the Wih row in 15 named float4s (scalar-kernel-sized register set);
// x tile staged to LDS, broadcast reads; 2 passes of 8 accumulators.
// ---------------------------------------------------------------------------
__global__ __launch_bounds__(NTHR, 1) void gi_gemm_kernel(
    const float* __restrict__ x,      // chunk base: [row][60] contiguous
    const float* __restrict__ Wih,    // [180][60]
    const float* __restrict__ bih,
    float* __restrict__ gi)           // chunk base: [row][180]
{
  __shared__ __align__(16) float xs[16 * 60];
  const int tid = threadIdx.x;
  const size_t row0 = (size_t)blockIdx.x * 16;
  const int rr = (tid < G) ? tid : 0;

  float4 W0, W1, W2, W3, W4, W5, W6, W7, W8, W9, W10, W11, W12, W13, W14;
#define LW(i) W##i = *(const float4*)&Wih[(size_t)rr * H + (i) * 4];
  LW(0) LW(1) LW(2) LW(3) LW(4) LW(5) LW(6) LW(7)
  LW(8) LW(9) LW(10) LW(11) LW(12) LW(13) LW(14)
#undef LW
  const float bi = bih[rr];

  {
    const float4* s4 = (const float4*)(x + row0 * H);
    float4* d4 = (float4*)xs;
    d4[tid] = s4[tid];                       // 0..191
    const int i2 = tid + NTHR;
    if (i2 < 240) d4[i2] = s4[i2];           // 192..239
  }
  __syncthreads();

#define GX(s, a)                                                      \
  {                                                                   \
    const float4 xv = *(const float4*)&xb[(s) * H + 4 * kk];          \
    a = fmaf(w.x, xv.x, a); a = fmaf(w.y, xv.y, a);                   \
    a = fmaf(w.z, xv.z, a); a = fmaf(w.w, xv.w, a);                   \
  }
#define PASS(p)                                                       \
  {                                                                   \
    const float* xb = xs + (p) * 8 * H;                               \
    float a0 = bi, a1 = bi, a2 = bi, a3 = bi;                         \
    float a4 = bi, a5 = bi, a6 = bi, a7 = bi;                         \
    _Pragma("unroll")                                                 \
    for (int kk = 0; kk < 15; ++kk) {                                 \
      float4 w;                                                       \
      switch (kk) {                                                   \
        case 0: w = W0; break;   case 1: w = W1; break;               \
        case 2: w = W2; break;   case 3: w = W3; break;               \
        case 4: w = W4; break;   case 5: w = W5; break;               \
        case 6: w = W6; break;   case 7: w = W7; break;               \
        case 8: w = W8; break;   case 9: w = W9; break;               \
        case 10: w = W10; break; case 11: w = W11; break;             \
        case 12: w = W12; break; case 13: w = W13; break;             \
        default: w = W14; break;                                      \
      }                                                               \
      GX(0, a0) GX(1, a1) GX(2, a2) GX(3, a3)                         \
      GX(4, a4) GX(5, a5) GX(6, a6) GX(7, a7)                         \
    }                                                                 \
    if (tid < G) {                                                    \
      float* o = gi + (row0 + (p) * 8) * G + rr;                      \
      o[0 * G] = a0; o[1 * G] = a1; o[2 * G] = a2; o[3 * G] = a3;     \
      o[4 * G] = a4; o[5 * G] = a5; o[6 * G] = a6; o[7 * G] = a7;     \
    }                                                                 \
  }
  PASS(0)
  PASS(1)
#undef PASS
#undef GX
}

// ---------------------------------------------------------------------------
// Recurrent layer consuming precomputed gi (= bih + Wih.x): byte-for-byte the
// proven scalar-kernel structure, with `a` streamed from global gi (720 B per
// block-step, coalesced, 4-deep register prefetch).
// ---------------------------------------------------------------------------
template <bool WRITE_YS, bool WRITE_PRED>
__global__ __launch_bounds__(NTHR, 1) void gru_rec_kernel(
    const float* __restrict__ gi,      // [nsteps][B][180] chunk-local
    const float* __restrict__ Whh, const float* __restrict__ bhh,
    const float* __restrict__ h_in, int h_in_stride,  // null => zeros
    float* __restrict__ ys_out,        // chunk base [nsteps][B][60] (if WRITE_YS)
    float* __restrict__ h_out,         // [B][60] carry
    float* __restrict__ enc_out,       // [b*180+j] or null
    float* __restrict__ pred_out,      // [B][T] (if WRITE_PRED)
    const float* __restrict__ linW, const float* __restrict__ linb,
    int t0, int nsteps)
{
  const int tid = threadIdx.x;
  const int b = blockIdx.x;

  __shared__ __align__(16) float h_sh[64];
  __shared__ float Ar[60], Az[60], Nn[60], Hn[60];
  __shared__ float pv[64];

  const int rr = (tid < G) ? tid : 0;

  float4 Wh0, Wh1, Wh2, Wh3, Wh4, Wh5, Wh6, Wh7, Wh8, Wh9, Wh10, Wh11, Wh12, Wh13, Wh14;
#define LWH(i) Wh##i = *(const float4*)&Whh[(size_t)rr * H + (i) * 4];
  LWH(0) LWH(1) LWH(2) LWH(3) LWH(4) LWH(5) LWH(6) LWH(7)
  LWH(8) LWH(9) LWH(10) LWH(11) LWH(12) LWH(13) LWH(14)
#undef LWH
  const float bh = bhh[rr];

  float linw = 0.f, lb = 0.f;
  if constexpr (WRITE_PRED) {
    linw = linW[tid < H ? tid : 0];
    lb = linb[0];
  }

  if (tid < H) h_sh[tid] = h_in ? h_in[(size_t)b * h_in_stride + tid] : 0.f;
  if (tid >= H && tid < 64) h_sh[tid] = 0.f;
  __syncthreads();

  const int g = rr / H;
  const int j = rr - g * H;
  const bool rowact = tid < G;

  // 4-deep gi prefetch (nsteps >= 4 always: T/NCH >= 8)
  float g0 = 0.f, g1 = 0.f, g2 = 0.f, g3 = 0.f;
  if (rowact) {
    g0 = gi[((size_t)0 * B + b) * G + rr];
    g1 = gi[((size_t)1 * B + b) * G + rr];
    g2 = gi[((size_t)2 * B + b) * G + rr];
    g3 = gi[((size_t)3 * B + b) * G + rr];
  }

  for (int s = 0; s < nsteps; ++s) {
    float gn = 0.f;
    if (rowact && s + 4 < nsteps) gn = gi[((size_t)(s + 4) * B + b) * G + rr];

    if (rowact) {
      float c0 = bh, c1 = 0.f, c2 = 0.f, c3 = 0.f;
      ACCH(0, c0) ACCH(1, c1) ACCH(2, c2) ACCH(3, c3)
      ACCH(4, c0) ACCH(5, c1) ACCH(6, c2) ACCH(7, c3)
      ACCH(8, c0) ACCH(9, c1) ACCH(10, c2) ACCH(11, c3)
      ACCH(12, c0) ACCH(13, c1) ACCH(14, c2)
      const float c = (c0 + c1) + (c2 + c3);
      const float a = g0;
      if (g == 0)       Ar[j] = a + c;
      else if (g == 1)  Az[j] = a + c;
      else            { Nn[j] = a; Hn[j] = c; }
    }
    g0 = g1; g1 = g2; g2 = g3; g3 = gn;
    __syncthreads();

    if (tid < H) {
      const float rg = sigm(Ar[tid]);
      const float zg = sigm(Az[tid]);
      const float nv = tanh_fast(fmaf(rg, Hn[tid], Nn[tid]));
      const float hnew = fmaf(zg, h_sh[tid] - nv, nv);
      h_sh[tid] = hnew;
      if constexpr (WRITE_YS)
        ys_out[(size_t)s * B * H + (size_t)b * H + tid] = hnew;
      if constexpr (WRITE_PRED) pv[tid] = hnew * linw;
    }
    __syncthreads();

    if constexpr (WRITE_PRED) {
      if (tid < 64) {
        float v = (tid < H) ? pv[tid] : 0.f;
#pragma unroll
        for (int o = 32; o; o >>= 1) v += __shfl_xor(v, o);
        if (tid == 0) pred_out[(size_t)b * T + t0 + s] = v + lb;
      }
    }
  }

  if (tid < H) {
    h_out[(size_t)b * H + tid] = h_sh[tid];
    if (enc_out) enc_out[(size_t)b * G + tid] = h_sh[tid];
  }
}

// ---------------------------------------------------------------------------
// One vector-input layer = NCH x (gemm chunk -> rec chunk). ys is consumed
// chunk-by-chunk by the gemm just before rec overwrites the same chunk, so a
// single ys buffer + a single gi chunk buffer suffice.
// ---------------------------------------------------------------------------
template <bool WRITE_YS, bool WRITE_PRED>
void run_vec_layer(const float* Wih, const float* bih,
                   const float* Whh, const float* bhh,
                   const float* h_init_slot,          // stride 180, may be null
                   float* enc_slot_out,               // may be null
                   float* ysA, float* gic, float* hio,
                   float* pred, const float* linW, const float* linb,
                   int nch, hipStream_t stream) {
  const int tn = T / nch;
  for (int c = 0; c < nch; ++c) {
    const int t0 = c * tn;
    gi_gemm_kernel<<<dim3((tn * B) / 16), dim3(NTHR), 0, stream>>>(
        ysA + (size_t)t0 * B * H, Wih, bih, gic);
    gru_rec_kernel<WRITE_YS, WRITE_PRED><<<dim3(B), dim3(NTHR), 0, stream>>>(
        gic, Whh, bhh,
        c ? hio : h_init_slot, c ? H : G,
        ysA + (size_t)t0 * B * H, hio,
        (c == nch - 1) ? enc_slot_out : nullptr,
        pred, linW, linb, t0, tn);
  }
}

}  // namespace

extern "C" void kernel_launch(void* const* d_in, const int* in_sizes, int n_in,
                              void* d_out, int out_size, void* d_ws, size_t ws_size,
                              hipStream_t stream) {
  const float* inputs  = (const float*)d_in[0];
  const float* outputs = (const float*)d_in[1];
  const float* eW_ih0 = (const float*)d_in[2];  const float* eW_hh0 = (const float*)d_in[3];
  const float* eb_ih0 = (const float*)d_in[4];  const float* eb_hh0 = (const float*)d_in[5];
  const float* eW_ih1 = (const float*)d_in[6];  const float* eW_hh1 = (const float*)d_in[7];
  const float* eb_ih1 = (const float*)d_in[8];  const float* eb_hh1 = (const float*)d_in[9];
  const float* eW_ih2 = (const float*)d_in[10]; const float* eW_hh2 = (const float*)d_in[11];
  const float* eb_ih2 = (const float*)d_in[12]; const float* eb_hh2 = (const float*)d_in[13];
  const float* c1_Wih = (const float*)d_in[14]; const float* c1_Whh = (const float*)d_in[15];
  const float* c1_bih = (const float*)d_in[16]; const float* c1_bhh = (const float*)d_in[17];
  const float* c2_Wih = (const float*)d_in[18]; const float* c2_Whh = (const float*)d_in[19];
  const float* c2_bih = (const float*)d_in[20]; const float* c2_bhh = (const float*)d_in[21];
  const float* c3_Wih = (const float*)d_in[22]; const float* c3_Whh = (const float*)d_in[23];
  const float* c3_bih = (const float*)d_in[24]; const float* c3_bhh = (const float*)d_in[25];
  const float* lin_W  = (const float*)d_in[26]; const float* lin_b  = (const float*)d_in[27];

  float* pred = (float*)d_out;                 // [B][T]
  float* enc  = pred + (size_t)B * T;          // [B][3][60]

  const size_t seq = (size_t)T * B * H;        // ys elements

  // pick chunk count: ys fp32 + gi fp32 chunk + h-carry must fit in ws
  int nch = 64;
  for (int c : {1, 2, 4, 8, 16, 32}) {
    const size_t need = seq * 4 + (size_t)(T / c) * B * G * 4 + (size_t)B * H * 4;
    if (ws_size >= need) { nch = c; break; }
  }

  float* ysA = (float*)d_ws;                        // [T][B][60] fp32
  float* gic = ysA + seq;                           // [(T/nch)][B][180] fp32
  float* hio = gic + (size_t)(T / nch) * B * G;     // [B][60] fp32

  // ---- encoder ----
  gru_scalar_kernel<true, true><<<dim3(B), dim3(NTHR), 0, stream>>>(
      inputs, eW_ih0, eW_hh0, eb_ih0, eb_hh0, nullptr, ysA, enc + 0);
  run_vec_layer<true, false>(eW_ih1, eb_ih1, eW_hh1, eb_hh1, nullptr, enc + 60,
                             ysA, gic, hio, pred, lin_W, lin_b, nch, stream);
  run_vec_layer<false, false>(eW_ih2, eb_ih2, eW_hh2, eb_hh2, nullptr, enc + 120,
                              ysA, gic, hio, pred, lin_W, lin_b, nch, stream);

  // ---- decoder: h1<-enc[2], h2<-enc[1], h3<-enc[0] ----
  gru_scalar_kernel<true, false><<<dim3(B), dim3(NTHR), 0, stream>>>(
      outputs, c1_Wih, c1_Whh, c1_bih, c1_bhh, enc + 120, ysA, nullptr);
  run_vec_layer<true, false>(c2_Wih, c2_bih, c2_Whh, c2_bhh, enc + 60, nullptr,
                             ysA, gic, hio, pred, lin_W, lin_b, nch, stream);
  run_vec_layer<false, true>(c3_Wih, c3_bih, c3_Whh, c3_bhh, enc + 0, nullptr,
                             ysA, gic, hio, pred, lin_W, lin_b, nch, stream);
}